// Round 3
// baseline (646.573 us; speedup 1.0000x reference)
//
#include <hip/hip_runtime.h>

#define D_MODEL 2048
#define NHEADS  16
#define DK      128
#define BATCH   2
#define SEQ     2048
#define MTOT    (BATCH*SEQ)   // 4096 rows

typedef unsigned short u16;
typedef unsigned int   u32;
typedef __bf16 bf16x8 __attribute__((ext_vector_type(8)));
typedef float  f32x4  __attribute__((ext_vector_type(4)));

__device__ __forceinline__ float b2f(u16 u) {
  return __uint_as_float(((u32)u) << 16);
}
__device__ __forceinline__ u16 f2b(float f) {  // RNE fp32 -> bf16
  u32 x = __float_as_uint(f);
  x += 0x7fffu + ((x >> 16) & 1u);
  return (u16)(x >> 16);
}

// async global->LDS, 16B per lane; dest = uniform base + lane*16 (m97 pattern)
__device__ __forceinline__ void gl2lds16(const u16* g, u16* l) {
  __builtin_amdgcn_global_load_lds(
      (const __attribute__((address_space(1))) void*)g,
      (__attribute__((address_space(3))) void*)l, 16, 0, 0);
}

// ---------------- fp32 -> bf16 bulk convert ----------------
__global__ __launch_bounds__(256) void cvt_k(const float* __restrict__ in,
                                             u16* __restrict__ out, int n4) {
  int i = blockIdx.x * 256 + threadIdx.x;
  if (i >= n4) return;
  float4 v = ((const float4*)in)[i];
  u32 lo = (u32)f2b(v.x) | ((u32)f2b(v.y) << 16);
  u32 hi = (u32)f2b(v.z) | ((u32)f2b(v.w) << 16);
  ((uint2*)out)[i] = make_uint2(lo, hi);
}

// 4 weight matrices in one dispatch (blockIdx.y selects)
__global__ __launch_bounds__(256) void cvt4_k(const float* __restrict__ a, const float* __restrict__ b,
                                              const float* __restrict__ c, const float* __restrict__ d,
                                              u16* __restrict__ oa, u16* __restrict__ ob,
                                              u16* __restrict__ oc, u16* __restrict__ od, int n4) {
  int z = blockIdx.y;
  const float* in = (z == 0) ? a : (z == 1) ? b : (z == 2) ? c : d;
  u16* out = (z == 0) ? oa : (z == 1) ? ob : (z == 2) ? oc : od;
  int i = blockIdx.x * 256 + threadIdx.x;
  if (i >= n4) return;
  float4 v = ((const float4*)in)[i];
  u32 lo = (u32)f2b(v.x) | ((u32)f2b(v.y) << 16);
  u32 hi = (u32)f2b(v.z) | ((u32)f2b(v.w) << 16);
  ((uint2*)out)[i] = make_uint2(lo, hi);
}

// ---------------- RoPE (in-place on bf16 (B,H,S,DK)) ----------------
__global__ __launch_bounds__(256) void rope_k(u16* __restrict__ T) {
  int idx = blockIdx.x * 256 + threadIdx.x;   // one thread per (bh,s,pair)
  int p = idx & 63;
  int s = (idx >> 6) & (SEQ - 1);
  float freq = exp2f(-0.20762050593045951f * (float)p);
  float ang = (float)s * freq;
  float sn, cs;
  sincosf(ang, &sn, &cs);
  u32 v = *(u32*)(T + (size_t)idx * 2);
  float te = b2f((u16)(v & 0xffffu));
  float to = b2f((u16)(v >> 16));
  float e  = te * cs - to * sn;
  float od = te * sn + to * cs;
  u32 r = (u32)f2b(e) | ((u32)f2b(od) << 16);
  *(u32*)(T + (size_t)idx * 2) = r;
}

// ---------------- GEMM: Y(M,N) = A(M,K) @ B(N,K)^T, bf16 MFMA ----------------
// m97 structure: global_load_lds(16B) into fragment-major LDS, 128x128 tile, BK=32.
// mode 0: outf[row*N+col] = acc + bias[col]           (fp32, O-proj, N=2048)
// mode 1: fused QKV scatter, N=6144: col>>11 selects Q/K/V, writes (B,H,S,DK) bf16
__global__ __launch_bounds__(256) void gemm_bt(const u16* __restrict__ A,
                                               const u16* __restrict__ B,
                                               const int M, const int N, const int K,
                                               u16* __restrict__ outb,
                                               float* __restrict__ outf,
                                               const float* __restrict__ bias,
                                               const int mode) {
  __shared__ __align__(16) u16 As[8 * 512];  // 8 fragment blocks (16 rows x 32 k each)
  __shared__ __align__(16) u16 Bs[8 * 512];

  const int t    = threadIdx.x;
  const int lane = t & 63;
  const int wave = t >> 6;
  const int wm   = wave >> 1, wn = wave & 1;
  const int quad = lane >> 4, l16 = lane & 15;
  const int m0 = blockIdx.y * 128, n0 = blockIdx.x * 128;
  const int sr = lane & 15, sc = lane >> 4;   // staging: row-in-block, 16B col group

  // each wave stages A blocks {2w,2w+1} and B blocks {2w,2w+1}
  const u16* ap0 = A + (size_t)(m0 + (wave * 2 + 0) * 16 + sr) * K + sc * 8;
  const u16* ap1 = A + (size_t)(m0 + (wave * 2 + 1) * 16 + sr) * K + sc * 8;
  const u16* bp0 = B + (size_t)(n0 + (wave * 2 + 0) * 16 + sr) * K + sc * 8;
  const u16* bp1 = B + (size_t)(n0 + (wave * 2 + 1) * 16 + sr) * K + sc * 8;
  u16* ad0 = As + (wave * 2 + 0) * 512;
  u16* ad1 = As + (wave * 2 + 1) * 512;
  u16* bd0 = Bs + (wave * 2 + 0) * 512;
  u16* bd1 = Bs + (wave * 2 + 1) * 512;

  f32x4 acc[4][4] = {};

  for (int k0 = 0; k0 < K; k0 += 32) {
    __syncthreads();                 // prior frag reads done before DMA overwrite
    gl2lds16(ap0 + k0, ad0);
    gl2lds16(ap1 + k0, ad1);
    gl2lds16(bp0 + k0, bd0);
    gl2lds16(bp1 + k0, bd1);
    __syncthreads();                 // drains vmcnt -> DMA landed

    bf16x8 af[4], bfr[4];
#pragma unroll
    for (int i = 0; i < 4; ++i)
      af[i] = *(const bf16x8*)&As[(wm * 4 + i) * 512 + lane * 8];
#pragma unroll
    for (int j = 0; j < 4; ++j)
      bfr[j] = *(const bf16x8*)&Bs[(wn * 4 + j) * 512 + lane * 8];
#pragma unroll
    for (int i = 0; i < 4; ++i)
#pragma unroll
      for (int j = 0; j < 4; ++j)
        acc[i][j] = __builtin_amdgcn_mfma_f32_16x16x32_bf16(af[i], bfr[j], acc[i][j], 0, 0, 0);
  }

#pragma unroll
  for (int i = 0; i < 4; ++i) {
#pragma unroll
    for (int j = 0; j < 4; ++j) {
#pragma unroll
      for (int rr = 0; rr < 4; ++rr) {
        int row = m0 + wm * 64 + i * 16 + quad * 4 + rr;
        int col = n0 + wn * 64 + j * 16 + l16;
        float v = acc[i][j][rr];
        if (mode == 0) {
          outf[(size_t)row * N + col] = v + bias[col];
        } else {
          int tens = col >> 11;          // 0=Q 1=K 2=V (dest buffers contiguous)
          int c2 = col & 2047;
          int b = row >> 11;
          int s = row & (SEQ - 1);
          int h = c2 >> 7;
          int d = c2 & (DK - 1);
          outb[(size_t)tens * 8388608 + (((size_t)(b * NHEADS + h)) * SEQ + s) * DK + d] = f2b(v);
        }
      }
    }
  }
}

// ---------------- V transpose: (B,H,S,DK) -> (B,H,DK,S), bf16 ----------------
__global__ __launch_bounds__(256) void vt_k(const u16* __restrict__ V,
                                            u16* __restrict__ Vt) {
  constexpr int LDT = 72;
  __shared__ __align__(16) u16 tile[64 * LDT];
  const int s0 = blockIdx.x * 64, d0 = blockIdx.y * 64, bh = blockIdx.z;
  const u16* in = V + (size_t)bh * SEQ * DK;
  u16* out = Vt + (size_t)bh * DK * SEQ;
  const int t = threadIdx.x;
  const int r = t >> 3, cg = t & 7;
#pragma unroll
  for (int half = 0; half < 2; ++half) {
    uint4 v = *(const uint4*)(in + (size_t)(s0 + r + half * 32) * DK + d0 + cg * 8);
    *(uint4*)&tile[(r + half * 32) * LDT + cg * 8] = v;
  }
  __syncthreads();
#pragma unroll
  for (int half = 0; half < 2; ++half) {
    int d = (t >> 3) + half * 32;
    __align__(16) u16 tmp[8];
#pragma unroll
    for (int i = 0; i < 8; ++i) tmp[i] = tile[(cg * 8 + i) * LDT + d];
    *(uint4*)(out + (size_t)(d0 + d) * SEQ + s0 + cg * 8) = *(const uint4*)tmp;
  }
}

// ---------------- MFMA flash attention, causal, transposed-softmax ----------------
// Q,K: bf16 (B,H,S,DK) roped. Vt: bf16 (B,H,DK,S). out: bf16 (B,S,D_MODEL).
// Block = 128 queries (4 waves x 32q in 2 groups of 16), key tile = 64.
// S computed transposed (col=q): mfma(kf, qf) -> per-lane softmax state for q=l16.
#define LDPS 72
__global__ __launch_bounds__(256) void attn_k(const u16* __restrict__ Q,
                                              const u16* __restrict__ K,
                                              const u16* __restrict__ Vt,
                                              u16* __restrict__ out) {
  __shared__ __align__(16) u16 smem[8192 + 8192 + 4 * 2 * 16 * LDPS];  // Ks,Vs,Ps = 51200B
  u16* Ks = smem;              // 16 blocks of 512: (nt*4+kc), frag-major
  u16* Vs = smem + 8192;       // 16 blocks of 512: (kcp*8+nt), frag-major

  const int t    = threadIdx.x;
  const int lane = t & 63;
  const int wave = t >> 6;
  const int quad = lane >> 4, l16 = lane & 15;
  u16* Psw = smem + 16384 + wave * (2 * 16 * LDPS);
  const int qt = (int)gridDim.x - 1 - (int)blockIdx.x;  // heavy blocks first
  const int bh = blockIdx.y;
  const size_t baseQK = (size_t)bh * SEQ * DK;
  const size_t baseV  = (size_t)bh * DK * SEQ;
  const int qw = qt * 128 + wave * 32;          // wave's first query row
  const float scale = 0.08838834764831845f;     // 1/sqrt(128)

  // Q frags (B-operand), held in regs: 2 groups x 4 k-chunks
  bf16x8 qf[2][4];
#pragma unroll
  for (int g = 0; g < 2; ++g)
#pragma unroll
    for (int kc = 0; kc < 4; ++kc)
      qf[g][kc] = *(const bf16x8*)(Q + baseQK + (size_t)(qw + g * 16 + l16) * DK + kc * 32 + quad * 8);

  f32x4 oacc[2][8] = {};
  float m_run[2] = {-1e30f, -1e30f};
  float l_run[2] = {0.f, 0.f};

  // staging: 4 K-instrs + 4 V-instrs per wave per tile
  const int sr = lane & 15, sc = lane >> 4;
  const u16* kp[4]; u16* kd[4];
  const u16* vp[4]; u16* vd[4];
#pragma unroll
  for (int j = 0; j < 4; ++j) {
    int lin = wave * 4 + j;
    int knt = lin >> 2, kkc = lin & 3;
    kp[j] = K + baseQK + (size_t)(knt * 16 + sr) * DK + kkc * 32 + sc * 8;
    kd[j] = Ks + lin * 512;
    int vkc = lin >> 3, vnt = lin & 7;
    vp[j] = Vt + baseV + (size_t)(vnt * 16 + sr) * SEQ + vkc * 32 + sc * 8;
    vd[j] = Vs + lin * 512;
  }

  const int kend = (qt + 1) * 128;
  for (int k0 = 0; k0 < kend; k0 += 64) {
    __syncthreads();
#pragma unroll
    for (int j = 0; j < 4; ++j) gl2lds16(kp[j], kd[j]);
#pragma unroll
    for (int j = 0; j < 4; ++j) gl2lds16(vp[j], vd[j]);
#pragma unroll
    for (int j = 0; j < 4; ++j) { kp[j] += (size_t)64 * DK; vp[j] += 64; }
    __syncthreads();

    if (k0 >= qw + 32) continue;        // wave-uniform causal skip (both groups masked)
    const bool g0on = (k0 < qw + 16);

    // ---- S^T = K . Q^T : per group, 4 tiles of 16(key)x16(q) ----
    f32x4 s0[4] = {}, s1[4] = {};
#pragma unroll
    for (int kc = 0; kc < 4; ++kc) {
#pragma unroll
      for (int nt = 0; nt < 4; ++nt) {
        bf16x8 kf = *(const bf16x8*)&Ks[(nt * 4 + kc) * 512 + lane * 8];
        if (g0on)
          s0[nt] = __builtin_amdgcn_mfma_f32_16x16x32_bf16(kf, qf[0][kc], s0[nt], 0, 0, 0);
        s1[nt] = __builtin_amdgcn_mfma_f32_16x16x32_bf16(kf, qf[1][kc], s1[nt], 0, 0, 0);
      }
    }

    // ---- per-group softmax (lane holds 16 keys for q = qw + g*16 + l16) ----
    auto softmax_g = [&](f32x4* sacc, int g) {
      const int qglob = qw + g * 16 + l16;
      float p[4][4];
      float newm = m_run[g];
#pragma unroll
      for (int nt = 0; nt < 4; ++nt)
#pragma unroll
        for (int r = 0; r < 4; ++r) {
          float v = sacc[nt][r] * scale;
          int key = k0 + nt * 16 + quad * 4 + r;
          v = (key <= qglob) ? v : -1e30f;
          p[nt][r] = v;
          newm = fmaxf(newm, v);
        }
      newm = fmaxf(newm, __shfl_xor(newm, 16));
      newm = fmaxf(newm, __shfl_xor(newm, 32));
      float lsum = 0.f;
#pragma unroll
      for (int nt = 0; nt < 4; ++nt)
#pragma unroll
        for (int r = 0; r < 4; ++r) {
          float e = __expf(p[nt][r] - newm);
          p[nt][r] = e;
          lsum += e;
        }
      lsum += __shfl_xor(lsum, 16);
      lsum += __shfl_xor(lsum, 32);
      float alpha = __expf(m_run[g] - newm);
      l_run[g] = l_run[g] * alpha + lsum;
      m_run[g] = newm;
      // P^T write: [q=l16][key], 4 packed keys per b64
      u16* pg = Psw + g * 16 * LDPS + l16 * LDPS;
#pragma unroll
      for (int nt = 0; nt < 4; ++nt) {
        u32 lo = (u32)f2b(p[nt][0]) | ((u32)f2b(p[nt][1]) << 16);
        u32 hi = (u32)f2b(p[nt][2]) | ((u32)f2b(p[nt][3]) << 16);
        *(uint2*)&pg[nt * 16 + quad * 4] = make_uint2(lo, hi);
      }
      // rescale O accumulator (alpha lives at lanes l16=q; need q=quad*4+r)
#pragma unroll
      for (int r = 0; r < 4; ++r) {
        float av = __shfl(alpha, quad * 4 + r);
#pragma unroll
        for (int nt = 0; nt < 8; ++nt) oacc[g][nt][r] *= av;
      }
    };
    if (g0on) softmax_g(s0, 0);
    softmax_g(s1, 1);

    // ---- PV: O[q][d] += P.V^T, vf shared across both groups ----
    const u16* pg0 = Psw + l16 * LDPS;
    const u16* pg1 = Psw + 16 * LDPS + l16 * LDPS;
#pragma unroll
    for (int kcp = 0; kcp < 2; ++kcp) {
      bf16x8 pf0 = *(const bf16x8*)&pg0[kcp * 32 + quad * 8];
      bf16x8 pf1 = *(const bf16x8*)&pg1[kcp * 32 + quad * 8];
#pragma unroll
      for (int nt = 0; nt < 8; ++nt) {
        bf16x8 vf = *(const bf16x8*)&Vs[(kcp * 8 + nt) * 512 + lane * 8];
        if (g0on)
          oacc[0][nt] = __builtin_amdgcn_mfma_f32_16x16x32_bf16(pf0, vf, oacc[0][nt], 0, 0, 0);
        oacc[1][nt] = __builtin_amdgcn_mfma_f32_16x16x32_bf16(pf1, vf, oacc[1][nt], 0, 0, 0);
      }
    }
  }

  // ---- epilogue: normalize + store (col = d = nt*16+l16, row = q) ----
  const int b = bh >> 4, h = bh & 15;
#pragma unroll
  for (int g = 0; g < 2; ++g) {
    float invl = 1.f / l_run[g];
#pragma unroll
    for (int r = 0; r < 4; ++r) {
      float iv = __shfl(invl, quad * 4 + r);
      int row = qt * 128 + wave * 32 + g * 16 + quad * 4 + r;
      size_t rb = ((size_t)(b * SEQ + row)) * D_MODEL + h * DK + l16;
#pragma unroll
      for (int nt = 0; nt < 8; ++nt)
        out[rb + nt * 16] = f2b(oacc[g][nt][r] * iv);
    }
  }
}

// ---------------- host-side orchestration ----------------
extern "C" void kernel_launch(void* const* d_in, const int* in_sizes, int n_in,
                              void* d_out, int out_size, void* d_ws, size_t ws_size,
                              hipStream_t stream) {
  const float* x  = (const float*)d_in[0];
  const float* wq = (const float*)d_in[1];
  const float* wk = (const float*)d_in[2];
  const float* wv = (const float*)d_in[3];
  const float* wo = (const float*)d_in[4];
  const float* bo = (const float*)d_in[5];
  float* out = (float*)d_out;

  char* wsb = (char*)d_ws;
  u16* xb    = (u16*)(wsb + 0);          // 16.78 MB (reused as attn output later)
  u16* wqb   = (u16*)(wsb + 16777216);   //  8.39 MB (wq/wk/wv contiguous => fused B)
  u16* wkb   = (u16*)(wsb + 25165824);
  u16* wvb   = (u16*)(wsb + 33554432);
  u16* wob   = (u16*)(wsb + 41943040);
  u16* Qb    = (u16*)(wsb + 50331648);   // Q/K/V contiguous => fused scatter dest
  u16* Kb    = (u16*)(wsb + 67108864);
  u16* Vb    = (u16*)(wsb + 83886080);
  u16* attnb = xb;                       // x's bf16 copy dead after QKV GEMM
  u16* Vtb   = wqb;                      // weights dead after QKV GEMM (16.78 MB span)

  // 1) convert inputs to bf16
  cvt_k<<<8192, 256, 0, stream>>>(x, xb, MTOT * D_MODEL / 4);
  cvt4_k<<<dim3(4096, 4), 256, 0, stream>>>(wq, wk, wv, wo, wqb, wkb, wvb, wob,
                                            D_MODEL * D_MODEL / 4);

  // 2) fused Q/K/V projection: one GEMM, N=6144 (wqb..wvb contiguous)
  gemm_bt<<<dim3(48, 32), 256, 0, stream>>>(xb, wqb, MTOT, 3 * D_MODEL, D_MODEL,
                                            Qb, nullptr, nullptr, 1);

  // 3) RoPE on Q and K; V transpose to (B,H,DK,S)
  rope_k<<<16384, 256, 0, stream>>>(Qb);
  rope_k<<<16384, 256, 0, stream>>>(Kb);
  vt_k<<<dim3(SEQ / 64, DK / 64, BATCH * NHEADS), 256, 0, stream>>>(Vb, Vtb);

  // 4) causal MFMA flash attention -> (B,S,D_MODEL) bf16
  attn_k<<<dim3(SEQ / 128, BATCH * NHEADS), 256, 0, stream>>>(Qb, Kb, Vtb, attnb);

  // 5) output projection + bias -> fp32 d_out
  gemm_bt<<<dim3(16, 32), 256, 0, stream>>>(attnb, wob, MTOT, D_MODEL, D_MODEL,
                                            nullptr, out, bo, 0);
}

// Round 4
// 566.368 us; speedup vs baseline: 1.1416x; 1.1416x over previous
//
#include <hip/hip_runtime.h>

#define D_MODEL 2048
#define NHEADS  16
#define DK      128
#define BATCH   2
#define SEQ     2048
#define MTOT    (BATCH*SEQ)   // 4096 rows

typedef unsigned short u16;
typedef unsigned int   u32;
typedef __bf16 bf16x8 __attribute__((ext_vector_type(8)));
typedef float  f32x4  __attribute__((ext_vector_type(4)));

__device__ __forceinline__ float b2f(u16 u) {
  return __uint_as_float(((u32)u) << 16);
}
__device__ __forceinline__ u16 f2b(float f) {  // RNE fp32 -> bf16
  u32 x = __float_as_uint(f);
  x += 0x7fffu + ((x >> 16) & 1u);
  return (u16)(x >> 16);
}

// async global->LDS, 16B per lane; dest = uniform base + lane*16 (m97 pattern)
__device__ __forceinline__ void gl2lds16(const u16* g, u16* l) {
  __builtin_amdgcn_global_load_lds(
      (const __attribute__((address_space(1))) void*)g,
      (__attribute__((address_space(3))) void*)l, 16, 0, 0);
}

// ---------------- fp32 -> bf16 bulk convert ----------------
__global__ __launch_bounds__(256) void cvt_k(const float* __restrict__ in,
                                             u16* __restrict__ out, int n4) {
  int i = blockIdx.x * 256 + threadIdx.x;
  if (i >= n4) return;
  float4 v = ((const float4*)in)[i];
  u32 lo = (u32)f2b(v.x) | ((u32)f2b(v.y) << 16);
  u32 hi = (u32)f2b(v.z) | ((u32)f2b(v.w) << 16);
  ((uint2*)out)[i] = make_uint2(lo, hi);
}

// 4 weight matrices in one dispatch (blockIdx.y selects)
__global__ __launch_bounds__(256) void cvt4_k(const float* __restrict__ a, const float* __restrict__ b,
                                              const float* __restrict__ c, const float* __restrict__ d,
                                              u16* __restrict__ oa, u16* __restrict__ ob,
                                              u16* __restrict__ oc, u16* __restrict__ od, int n4) {
  int z = blockIdx.y;
  const float* in = (z == 0) ? a : (z == 1) ? b : (z == 2) ? c : d;
  u16* out = (z == 0) ? oa : (z == 1) ? ob : (z == 2) ? oc : od;
  int i = blockIdx.x * 256 + threadIdx.x;
  if (i >= n4) return;
  float4 v = ((const float4*)in)[i];
  u32 lo = (u32)f2b(v.x) | ((u32)f2b(v.y) << 16);
  u32 hi = (u32)f2b(v.z) | ((u32)f2b(v.w) << 16);
  ((uint2*)out)[i] = make_uint2(lo, hi);
}

// ---------------- RoPE (in-place on bf16 (B,H,S,DK)), optional post-scale ----------------
__global__ __launch_bounds__(256) void rope_k(u16* __restrict__ T, float mult) {
  int idx = blockIdx.x * 256 + threadIdx.x;   // one thread per (bh,s,pair)
  int p = idx & 63;
  int s = (idx >> 6) & (SEQ - 1);
  float freq = exp2f(-0.20762050593045951f * (float)p);
  float ang = (float)s * freq;
  float sn, cs;
  sincosf(ang, &sn, &cs);
  u32 v = *(u32*)(T + (size_t)idx * 2);
  float te = b2f((u16)(v & 0xffffu));
  float to = b2f((u16)(v >> 16));
  float e  = (te * cs - to * sn) * mult;
  float od = (te * sn + to * cs) * mult;
  u32 r = (u32)f2b(e) | ((u32)f2b(od) << 16);
  *(u32*)(T + (size_t)idx * 2) = r;
}

// ---------------- GEMM: Y(M,N) = A(M,K) @ B(N,K)^T, bf16 MFMA ----------------
// m97 structure: global_load_lds(16B) into fragment-major LDS, 128x128 tile, BK=32.
// mode 0: outf[row*N+col] = acc + bias[col]           (fp32, O-proj, N=2048)
// mode 1: fused QKV scatter, N=6144: col>>11 selects Q/K/V, writes (B,H,S,DK) bf16
__global__ __launch_bounds__(256) void gemm_bt(const u16* __restrict__ A,
                                               const u16* __restrict__ B,
                                               const int M, const int N, const int K,
                                               u16* __restrict__ outb,
                                               float* __restrict__ outf,
                                               const float* __restrict__ bias,
                                               const int mode) {
  __shared__ __align__(16) u16 As[8 * 512];  // 8 fragment blocks (16 rows x 32 k each)
  __shared__ __align__(16) u16 Bs[8 * 512];

  const int t    = threadIdx.x;
  const int lane = t & 63;
  const int wave = t >> 6;
  const int wm   = wave >> 1, wn = wave & 1;
  const int quad = lane >> 4, l16 = lane & 15;
  const int m0 = blockIdx.y * 128, n0 = blockIdx.x * 128;
  const int sr = lane & 15, sc = lane >> 4;   // staging: row-in-block, 16B col group

  const u16* ap0 = A + (size_t)(m0 + (wave * 2 + 0) * 16 + sr) * K + sc * 8;
  const u16* ap1 = A + (size_t)(m0 + (wave * 2 + 1) * 16 + sr) * K + sc * 8;
  const u16* bp0 = B + (size_t)(n0 + (wave * 2 + 0) * 16 + sr) * K + sc * 8;
  const u16* bp1 = B + (size_t)(n0 + (wave * 2 + 1) * 16 + sr) * K + sc * 8;
  u16* ad0 = As + (wave * 2 + 0) * 512;
  u16* ad1 = As + (wave * 2 + 1) * 512;
  u16* bd0 = Bs + (wave * 2 + 0) * 512;
  u16* bd1 = Bs + (wave * 2 + 1) * 512;

  f32x4 acc[4][4] = {};

  for (int k0 = 0; k0 < K; k0 += 32) {
    __syncthreads();
    gl2lds16(ap0 + k0, ad0);
    gl2lds16(ap1 + k0, ad1);
    gl2lds16(bp0 + k0, bd0);
    gl2lds16(bp1 + k0, bd1);
    __syncthreads();

    bf16x8 af[4], bfr[4];
#pragma unroll
    for (int i = 0; i < 4; ++i)
      af[i] = *(const bf16x8*)&As[(wm * 4 + i) * 512 + lane * 8];
#pragma unroll
    for (int j = 0; j < 4; ++j)
      bfr[j] = *(const bf16x8*)&Bs[(wn * 4 + j) * 512 + lane * 8];
#pragma unroll
    for (int i = 0; i < 4; ++i)
#pragma unroll
      for (int j = 0; j < 4; ++j)
        acc[i][j] = __builtin_amdgcn_mfma_f32_16x16x32_bf16(af[i], bfr[j], acc[i][j], 0, 0, 0);
  }

#pragma unroll
  for (int i = 0; i < 4; ++i) {
#pragma unroll
    for (int j = 0; j < 4; ++j) {
#pragma unroll
      for (int rr = 0; rr < 4; ++rr) {
        int row = m0 + wm * 64 + i * 16 + quad * 4 + rr;
        int col = n0 + wn * 64 + j * 16 + l16;
        float v = acc[i][j][rr];
        if (mode == 0) {
          outf[(size_t)row * N + col] = v + bias[col];
        } else {
          int tens = col >> 11;          // 0=Q 1=K 2=V (dest buffers contiguous)
          int c2 = col & 2047;
          int b = row >> 11;
          int s = row & (SEQ - 1);
          int h = c2 >> 7;
          int d = c2 & (DK - 1);
          outb[(size_t)tens * 8388608 + (((size_t)(b * NHEADS + h)) * SEQ + s) * DK + d] = f2b(v);
        }
      }
    }
  }
}

// ---------------- V transpose: (B,H,S,DK) -> (B,H,DK,S), bf16 ----------------
__global__ __launch_bounds__(256) void vt_k(const u16* __restrict__ V,
                                            u16* __restrict__ Vt) {
  constexpr int LDT = 72;
  __shared__ __align__(16) u16 tile[64 * LDT];
  const int s0 = blockIdx.x * 64, d0 = blockIdx.y * 64, bh = blockIdx.z;
  const u16* in = V + (size_t)bh * SEQ * DK;
  u16* out = Vt + (size_t)bh * DK * SEQ;
  const int t = threadIdx.x;
  const int r = t >> 3, cg = t & 7;
#pragma unroll
  for (int half = 0; half < 2; ++half) {
    uint4 v = *(const uint4*)(in + (size_t)(s0 + r + half * 32) * DK + d0 + cg * 8);
    *(uint4*)&tile[(r + half * 32) * LDT + cg * 8] = v;
  }
  __syncthreads();
#pragma unroll
  for (int half = 0; half < 2; ++half) {
    int d = (t >> 3) + half * 32;
    __align__(16) u16 tmp[8];
#pragma unroll
    for (int i = 0; i < 8; ++i) tmp[i] = tile[(cg * 8 + i) * LDT + d];
    *(uint4*)(out + (size_t)(d0 + d) * SEQ + s0 + cg * 8) = *(const uint4*)tmp;
  }
}

// ---------------- MFMA flash attention, causal, transposed-softmax ----------------
// Q: bf16 (B,H,S,DK), roped AND pre-scaled by 1/sqrt(DK). K: roped. Vt: (B,H,DK,S).
// out: bf16 (B,S,D_MODEL).
// Block = 64 queries (4 waves x 16q), key tile = 64, 1024 blocks, 4 blocks/CU.
// S^T = mfma(kf, qf): lane l16 = q -> in-lane softmax + 2 shfl reductions.
// P kept in unpadded per-wave LDS with XOR swizzle (conflict-free b64 w / b128 r).
__global__ __launch_bounds__(256, 4) void attn_k(const u16* __restrict__ Q,
                                                 const u16* __restrict__ K,
                                                 const u16* __restrict__ Vt,
                                                 u16* __restrict__ out) {
  __shared__ __align__(16) u16 smem[8192 + 8192 + 4096];  // Ks, Vs, P = 40960B (4 blocks/CU)
  u16* Ks = smem;              // 16 blocks of 512: (nt*4+kc), frag-major
  u16* Vs = smem + 8192;       // 16 blocks of 512: (kcp*8+nt), frag-major

  const int t    = threadIdx.x;
  const int lane = t & 63;
  const int wave = t >> 6;
  const int quad = lane >> 4, l16 = lane & 15;
  u16* Psw = smem + 16384 + wave * 1024;        // 16q x 64k, swizzled
  const int pmask = (l16 & 7) << 3;             // XOR swizzle on key bits 3..5
  const int qt = (int)gridDim.x - 1 - (int)blockIdx.x;  // heavy blocks first
  const int bh = blockIdx.y;
  const size_t baseQK = (size_t)bh * SEQ * DK;
  const size_t baseV  = (size_t)bh * DK * SEQ;
  const int qw = qt * 64 + wave * 16;           // wave's first query row
  const int qglob = qw + l16;                   // this lane's query (transposed S)

  // Q frags (B-operand), held in regs (Q already scaled by 1/sqrt(DK) in rope)
  bf16x8 qf[4];
#pragma unroll
  for (int kc = 0; kc < 4; ++kc)
    qf[kc] = *(const bf16x8*)(Q + baseQK + (size_t)(qw + l16) * DK + kc * 32 + quad * 8);

  f32x4 oacc[8] = {};
  float m_run = -1e30f, l_run = 0.f;

  // staging: 4 K-instrs + 4 V-instrs per wave per tile
  const int sr = lane & 15, sc = lane >> 4;
  const u16* kp[4]; u16* kd[4];
  const u16* vp[4]; u16* vd[4];
#pragma unroll
  for (int j = 0; j < 4; ++j) {
    int lin = wave * 4 + j;
    int knt = lin >> 2, kkc = lin & 3;
    kp[j] = K + baseQK + (size_t)(knt * 16 + sr) * DK + kkc * 32 + sc * 8;
    kd[j] = Ks + lin * 512;
    int vkc = lin >> 3, vnt = lin & 7;
    vp[j] = Vt + baseV + (size_t)(vnt * 16 + sr) * SEQ + vkc * 32 + sc * 8;
    vd[j] = Vs + lin * 512;
  }

  const int kend = (qt + 1) * 64;
  for (int k0 = 0; k0 < kend; k0 += 64) {
    __syncthreads();
#pragma unroll
    for (int j = 0; j < 4; ++j) gl2lds16(kp[j], kd[j]);
#pragma unroll
    for (int j = 0; j < 4; ++j) gl2lds16(vp[j], vd[j]);
#pragma unroll
    for (int j = 0; j < 4; ++j) { kp[j] += (size_t)64 * DK; vp[j] += 64; }
    __syncthreads();

    if (k0 >= qw + 16) continue;        // wave-uniform causal skip (tail tiles)

    // ---- S^T = K . Q^T : 4 tiles of 16(key)x16(q) ----
    f32x4 s[4] = {};
#pragma unroll
    for (int kc = 0; kc < 4; ++kc) {
#pragma unroll
      for (int nt = 0; nt < 4; ++nt) {
        bf16x8 kf = *(const bf16x8*)&Ks[(nt * 4 + kc) * 512 + lane * 8];
        s[nt] = __builtin_amdgcn_mfma_f32_16x16x32_bf16(kf, qf[kc], s[nt], 0, 0, 0);
      }
    }

    // ---- softmax (lane holds 16 keys for q = qglob) ----
    float p[4][4];
    float newm = m_run;
    if (k0 + 63 > qw) {  // diagonal tile: per-lane causal mask (wave-uniform branch)
#pragma unroll
      for (int nt = 0; nt < 4; ++nt)
#pragma unroll
        for (int r = 0; r < 4; ++r) {
          int key = k0 + nt * 16 + quad * 4 + r;
          float v = (key <= qglob) ? s[nt][r] : -1e30f;
          p[nt][r] = v;
          newm = fmaxf(newm, v);
        }
    } else {             // fully unmasked tile
#pragma unroll
      for (int nt = 0; nt < 4; ++nt)
#pragma unroll
        for (int r = 0; r < 4; ++r) {
          p[nt][r] = s[nt][r];
          newm = fmaxf(newm, s[nt][r]);
        }
    }
    newm = fmaxf(newm, __shfl_xor(newm, 16));
    newm = fmaxf(newm, __shfl_xor(newm, 32));
    float lsum = 0.f;
#pragma unroll
    for (int nt = 0; nt < 4; ++nt)
#pragma unroll
      for (int r = 0; r < 4; ++r) {
        float e = __expf(p[nt][r] - newm);
        p[nt][r] = e;
        lsum += e;
      }
    lsum += __shfl_xor(lsum, 16);
    lsum += __shfl_xor(lsum, 32);
    float alpha = __expf(m_run - newm);
    l_run = l_run * alpha + lsum;
    m_run = newm;

    // ---- P^T write (swizzled, per-wave region; 4 b64 writes) ----
#pragma unroll
    for (int nt = 0; nt < 4; ++nt) {
      u32 lo = (u32)f2b(p[nt][0]) | ((u32)f2b(p[nt][1]) << 16);
      u32 hi = (u32)f2b(p[nt][2]) | ((u32)f2b(p[nt][3]) << 16);
      *(uint2*)&Psw[l16 * 64 + ((nt * 16 + quad * 4) ^ pmask)] = make_uint2(lo, hi);
    }

    // ---- rescale O accumulator (alpha lives at lane l16=q; rows need q=quad*4+r) ----
#pragma unroll
    for (int r = 0; r < 4; ++r) {
      float av = __shfl(alpha, quad * 4 + r);
#pragma unroll
      for (int nt = 0; nt < 8; ++nt) oacc[nt][r] *= av;
    }

    // ---- PV: O[q][d] += P . V^T ----
#pragma unroll
    for (int kcp = 0; kcp < 2; ++kcp) {
      bf16x8 pf = *(const bf16x8*)&Psw[l16 * 64 + ((kcp * 32 + quad * 8) ^ pmask)];
#pragma unroll
      for (int nt = 0; nt < 8; ++nt) {
        bf16x8 vf = *(const bf16x8*)&Vs[(kcp * 8 + nt) * 512 + lane * 8];
        oacc[nt] = __builtin_amdgcn_mfma_f32_16x16x32_bf16(pf, vf, oacc[nt], 0, 0, 0);
      }
    }
  }

  // ---- epilogue: normalize, stage to LDS (reuse Ks+Vs), coalesced b128 store ----
  constexpr int LDO = 136;  // 272B row stride: pads 64-row staging against bank aliasing
  float invl = 1.f / l_run;
  __syncthreads();  // all waves done with Ks/Vs reads
#pragma unroll
  for (int r = 0; r < 4; ++r) {
    float iv = __shfl(invl, quad * 4 + r);
#pragma unroll
    for (int nt = 0; nt < 8; ++nt)
      smem[(wave * 16 + quad * 4 + r) * LDO + nt * 16 + l16] = f2b(oacc[nt][r] * iv);
  }
  __syncthreads();
  const int b = bh >> 4, h = bh & 15;
#pragma unroll
  for (int pss = 0; pss < 4; ++pss) {
    int row = (t >> 4) + pss * 16;
    uint4 v = *(const uint4*)&smem[row * LDO + (t & 15) * 8];
    *(uint4*)(out + ((size_t)(b * SEQ + qt * 64 + row)) * D_MODEL + h * DK + (t & 15) * 8) = v;
  }
}

// ---------------- host-side orchestration ----------------
extern "C" void kernel_launch(void* const* d_in, const int* in_sizes, int n_in,
                              void* d_out, int out_size, void* d_ws, size_t ws_size,
                              hipStream_t stream) {
  const float* x  = (const float*)d_in[0];
  const float* wq = (const float*)d_in[1];
  const float* wk = (const float*)d_in[2];
  const float* wv = (const float*)d_in[3];
  const float* wo = (const float*)d_in[4];
  const float* bo = (const float*)d_in[5];
  float* out = (float*)d_out;

  char* wsb = (char*)d_ws;
  u16* xb    = (u16*)(wsb + 0);          // 16.78 MB (reused as attn output later)
  u16* wqb   = (u16*)(wsb + 16777216);   //  8.39 MB (wq/wk/wv contiguous => fused B)
  u16* wkb   = (u16*)(wsb + 25165824);
  u16* wvb   = (u16*)(wsb + 33554432);
  u16* wob   = (u16*)(wsb + 41943040);
  u16* Qb    = (u16*)(wsb + 50331648);   // Q/K/V contiguous => fused scatter dest
  u16* Kb    = (u16*)(wsb + 67108864);
  u16* Vb    = (u16*)(wsb + 83886080);
  u16* attnb = xb;                       // x's bf16 copy dead after QKV GEMM
  u16* Vtb   = wqb;                      // weights dead after QKV GEMM (16.78 MB span)

  // 1) convert inputs to bf16
  cvt_k<<<8192, 256, 0, stream>>>(x, xb, MTOT * D_MODEL / 4);
  cvt4_k<<<dim3(4096, 4), 256, 0, stream>>>(wq, wk, wv, wo, wqb, wkb, wvb, wob,
                                            D_MODEL * D_MODEL / 4);

  // 2) fused Q/K/V projection: one GEMM, N=6144 (wqb..wvb contiguous)
  gemm_bt<<<dim3(48, 32), 256, 0, stream>>>(xb, wqb, MTOT, 3 * D_MODEL, D_MODEL,
                                            Qb, nullptr, nullptr, 1);

  // 3) RoPE on Q (folding in 1/sqrt(DK)) and K; V transpose to (B,H,DK,S)
  rope_k<<<16384, 256, 0, stream>>>(Qb, 0.08838834764831845f);
  rope_k<<<16384, 256, 0, stream>>>(Kb, 1.0f);
  vt_k<<<dim3(SEQ / 64, DK / 64, BATCH * NHEADS), 256, 0, stream>>>(Vb, Vtb);

  // 4) causal MFMA flash attention -> (B,S,D_MODEL) bf16
  attn_k<<<dim3(SEQ / 64, BATCH * NHEADS), 256, 0, stream>>>(Qb, Kb, Vtb, attnb);

  // 5) output projection + bias -> fp32 d_out
  gemm_bt<<<dim3(16, 32), 256, 0, stream>>>(attnb, wob, MTOT, D_MODEL, D_MODEL,
                                            nullptr, out, bo, 0);
}

// Round 5
// 546.669 us; speedup vs baseline: 1.1828x; 1.0360x over previous
//
#include <hip/hip_runtime.h>

#define D_MODEL 2048
#define NHEADS  16
#define DK      128
#define BATCH   2
#define SEQ     2048
#define MTOT    (BATCH*SEQ)   // 4096 rows

typedef unsigned short u16;
typedef unsigned int   u32;
typedef __bf16 bf16x8 __attribute__((ext_vector_type(8)));
typedef float  f32x4  __attribute__((ext_vector_type(4)));

__device__ __forceinline__ float b2f(u16 u) {
  return __uint_as_float(((u32)u) << 16);
}
__device__ __forceinline__ u16 f2b(float f) {  // RNE fp32 -> bf16
  u32 x = __float_as_uint(f);
  x += 0x7fffu + ((x >> 16) & 1u);
  return (u16)(x >> 16);
}

// async global->LDS, 16B per lane; dest = uniform base + lane*16 (m97 pattern)
__device__ __forceinline__ void gl2lds16(const u16* g, u16* l) {
  __builtin_amdgcn_global_load_lds(
      (const __attribute__((address_space(1))) void*)g,
      (__attribute__((address_space(3))) void*)l, 16, 0, 0);
}

// ---------------- fp32 -> bf16 bulk convert ----------------
__global__ __launch_bounds__(256) void cvt_k(const float* __restrict__ in,
                                             u16* __restrict__ out, int n4) {
  int i = blockIdx.x * 256 + threadIdx.x;
  if (i >= n4) return;
  float4 v = ((const float4*)in)[i];
  u32 lo = (u32)f2b(v.x) | ((u32)f2b(v.y) << 16);
  u32 hi = (u32)f2b(v.z) | ((u32)f2b(v.w) << 16);
  ((uint2*)out)[i] = make_uint2(lo, hi);
}

// 4 weight matrices in one dispatch (blockIdx.y selects)
__global__ __launch_bounds__(256) void cvt4_k(const float* __restrict__ a, const float* __restrict__ b,
                                              const float* __restrict__ c, const float* __restrict__ d,
                                              u16* __restrict__ oa, u16* __restrict__ ob,
                                              u16* __restrict__ oc, u16* __restrict__ od, int n4) {
  int z = blockIdx.y;
  const float* in = (z == 0) ? a : (z == 1) ? b : (z == 2) ? c : d;
  u16* out = (z == 0) ? oa : (z == 1) ? ob : (z == 2) ? oc : od;
  int i = blockIdx.x * 256 + threadIdx.x;
  if (i >= n4) return;
  float4 v = ((const float4*)in)[i];
  u32 lo = (u32)f2b(v.x) | ((u32)f2b(v.y) << 16);
  u32 hi = (u32)f2b(v.z) | ((u32)f2b(v.w) << 16);
  ((uint2*)out)[i] = make_uint2(lo, hi);
}

// ---------------- GEMM: Y(M,N) = A(M,K) @ B(N,K)^T, bf16 MFMA ----------------
// m97 structure + BK=64: global_load_lds(16B) frag-major LDS, 128x128 tile.
// mode 0: outf[row*N+col] = acc + bias[col]           (fp32, O-proj, N=2048)
// mode 1: fused QKV scatter, N=6144 (col>>11: 0=Q,1=K,2=V) -> (B,H,S,DK) bf16,
//         with RoPE fused for Q/K (and 1/sqrt(DK) folded into Q).
__global__ __launch_bounds__(256) void gemm_bt(const u16* __restrict__ A,
                                               const u16* __restrict__ B,
                                               const int M, const int N, const int K,
                                               u16* __restrict__ outb,
                                               float* __restrict__ outf,
                                               const float* __restrict__ bias,
                                               const int mode) {
  __shared__ __align__(16) u16 As[16 * 512];  // 16 frag blocks (16 rows x 32 k): 16KB
  __shared__ __align__(16) u16 Bs[16 * 512];  // 16KB

  const int t    = threadIdx.x;
  const int lane = t & 63;
  const int wave = t >> 6;
  const int wm   = wave >> 1, wn = wave & 1;
  const int quad = lane >> 4, l16 = lane & 15;
  const int m0 = blockIdx.y * 128, n0 = blockIdx.x * 128;
  const int sr = lane & 15, sc = lane >> 4;   // staging: row-in-block, 16B col group

  // each wave stages 4 A-blocks + 4 B-blocks per BK=64 step
  const u16* ap[4]; u16* ad[4];
  const u16* bp[4]; u16* bd[4];
#pragma unroll
  for (int j = 0; j < 4; ++j) {
    int id = wave * 4 + j;            // 0..15
    int kc = id >> 3, mt = id & 7;    // block = (kc*8 + mt): 16 rows x 32 k
    ap[j] = A + (size_t)(m0 + mt * 16 + sr) * K + kc * 32 + sc * 8;
    ad[j] = As + id * 512;
    bp[j] = B + (size_t)(n0 + mt * 16 + sr) * K + kc * 32 + sc * 8;
    bd[j] = Bs + id * 512;
  }

  f32x4 acc[4][4] = {};

  for (int k0 = 0; k0 < K; k0 += 64) {
    __syncthreads();                 // prior frag reads done before DMA overwrite
    gl2lds16(ap[0] + k0, ad[0]);
    gl2lds16(ap[1] + k0, ad[1]);
    gl2lds16(ap[2] + k0, ad[2]);
    gl2lds16(ap[3] + k0, ad[3]);
    gl2lds16(bp[0] + k0, bd[0]);
    gl2lds16(bp[1] + k0, bd[1]);
    gl2lds16(bp[2] + k0, bd[2]);
    gl2lds16(bp[3] + k0, bd[3]);
    __syncthreads();                 // drains vmcnt -> DMA landed

#pragma unroll
    for (int kc = 0; kc < 2; ++kc) {
      bf16x8 af[4], bfr[4];
#pragma unroll
      for (int i = 0; i < 4; ++i)
        af[i] = *(const bf16x8*)&As[(kc * 8 + wm * 4 + i) * 512 + lane * 8];
#pragma unroll
      for (int j = 0; j < 4; ++j)
        bfr[j] = *(const bf16x8*)&Bs[(kc * 8 + wn * 4 + j) * 512 + lane * 8];
#pragma unroll
      for (int i = 0; i < 4; ++i)
#pragma unroll
        for (int j = 0; j < 4; ++j)
          acc[i][j] = __builtin_amdgcn_mfma_f32_16x16x32_bf16(af[i], bfr[j], acc[i][j], 0, 0, 0);
    }
  }

  if (mode == 0) {
#pragma unroll
    for (int i = 0; i < 4; ++i)
#pragma unroll
      for (int j = 0; j < 4; ++j)
#pragma unroll
        for (int rr = 0; rr < 4; ++rr) {
          int row = m0 + wm * 64 + i * 16 + quad * 4 + rr;
          int col = n0 + wn * 64 + j * 16 + l16;
          outf[(size_t)row * N + col] = acc[i][j][rr] + bias[col];
        }
  } else {
    // QKV scatter + fused RoPE. tens/h uniform per block (n0 % 128 == 0).
    const int tens = n0 >> 11;                 // 0=Q 1=K 2=V
    const int h    = (n0 & 2047) >> 7;
    const bool doRope = (tens < 2);
    const float mult = (tens == 0) ? 0.08838834764831845f : 1.0f;  // 1/sqrt(DK) on Q
#pragma unroll
    for (int j = 0; j < 4; ++j) {
      const int d = wn * 64 + j * 16 + l16;    // head-dim of this lane's column
      const float freq = exp2f(-0.20762050593045951f * (float)(d >> 1));
      const float sgn  = (d & 1) ? 1.f : -1.f;
#pragma unroll
      for (int i = 0; i < 4; ++i)
#pragma unroll
        for (int rr = 0; rr < 4; ++rr) {
          int row = m0 + wm * 64 + i * 16 + quad * 4 + rr;
          int b = row >> 11;
          int s = row & (SEQ - 1);
          float v = acc[i][j][rr];
          if (doRope) {
            float sn, cs;
            __sincosf((float)s * freq, &sn, &cs);
            float pv = __shfl_xor(v, 1);       // partner element of the (even,odd) pair
            v = (v * cs + sgn * pv * sn) * mult;
          }
          outb[(size_t)tens * 8388608 + (((size_t)(b * NHEADS + h)) * SEQ + s) * DK + d] = f2b(v);
        }
    }
  }
}

// ---------------- V transpose: (B,H,S,DK) -> (B,H,DK,S), bf16 ----------------
__global__ __launch_bounds__(256) void vt_k(const u16* __restrict__ V,
                                            u16* __restrict__ Vt) {
  constexpr int LDT = 72;
  __shared__ __align__(16) u16 tile[64 * LDT];
  const int s0 = blockIdx.x * 64, d0 = blockIdx.y * 64, bh = blockIdx.z;
  const u16* in = V + (size_t)bh * SEQ * DK;
  u16* out = Vt + (size_t)bh * DK * SEQ;
  const int t = threadIdx.x;
  const int r = t >> 3, cg = t & 7;
#pragma unroll
  for (int half = 0; half < 2; ++half) {
    uint4 v = *(const uint4*)(in + (size_t)(s0 + r + half * 32) * DK + d0 + cg * 8);
    *(uint4*)&tile[(r + half * 32) * LDT + cg * 8] = v;
  }
  __syncthreads();
#pragma unroll
  for (int half = 0; half < 2; ++half) {
    int d = (t >> 3) + half * 32;
    __align__(16) u16 tmp[8];
#pragma unroll
    for (int i = 0; i < 8; ++i) tmp[i] = tile[(cg * 8 + i) * LDT + d];
    *(uint4*)(out + (size_t)(d0 + d) * SEQ + s0 + cg * 8) = *(const uint4*)tmp;
  }
}

// ---------------- MFMA flash attention, causal, transposed-softmax ----------------
// Q: bf16 (B,H,S,DK), roped AND pre-scaled by 1/sqrt(DK). K: roped. Vt: (B,H,DK,S).
// out: bf16 (B,S,D_MODEL).
__global__ __launch_bounds__(256, 4) void attn_k(const u16* __restrict__ Q,
                                                 const u16* __restrict__ K,
                                                 const u16* __restrict__ Vt,
                                                 u16* __restrict__ out) {
  __shared__ __align__(16) u16 smem[8192 + 8192 + 4096];  // Ks, Vs, P = 40960B
  u16* Ks = smem;              // 16 blocks of 512: (nt*4+kc), frag-major
  u16* Vs = smem + 8192;       // 16 blocks of 512: (kcp*8+nt), frag-major

  const int t    = threadIdx.x;
  const int lane = t & 63;
  const int wave = t >> 6;
  const int quad = lane >> 4, l16 = lane & 15;
  u16* Psw = smem + 16384 + wave * 1024;        // 16q x 64k, swizzled
  const int pmask = (l16 & 7) << 3;             // XOR swizzle on key bits 3..5
  const int qt = (int)gridDim.x - 1 - (int)blockIdx.x;  // heavy blocks first
  const int bh = blockIdx.y;
  const size_t baseQK = (size_t)bh * SEQ * DK;
  const size_t baseV  = (size_t)bh * DK * SEQ;
  const int qw = qt * 64 + wave * 16;           // wave's first query row
  const int qglob = qw + l16;                   // this lane's query (transposed S)

  bf16x8 qf[4];
#pragma unroll
  for (int kc = 0; kc < 4; ++kc)
    qf[kc] = *(const bf16x8*)(Q + baseQK + (size_t)(qw + l16) * DK + kc * 32 + quad * 8);

  f32x4 oacc[8] = {};
  float m_run = -1e30f, l_run = 0.f;

  const int sr = lane & 15, sc = lane >> 4;
  const u16* kp[4]; u16* kd[4];
  const u16* vp[4]; u16* vd[4];
#pragma unroll
  for (int j = 0; j < 4; ++j) {
    int lin = wave * 4 + j;
    int knt = lin >> 2, kkc = lin & 3;
    kp[j] = K + baseQK + (size_t)(knt * 16 + sr) * DK + kkc * 32 + sc * 8;
    kd[j] = Ks + lin * 512;
    int vkc = lin >> 3, vnt = lin & 7;
    vp[j] = Vt + baseV + (size_t)(vnt * 16 + sr) * SEQ + vkc * 32 + sc * 8;
    vd[j] = Vs + lin * 512;
  }

  const int kend = (qt + 1) * 64;
  for (int k0 = 0; k0 < kend; k0 += 64) {
    __syncthreads();
#pragma unroll
    for (int j = 0; j < 4; ++j) gl2lds16(kp[j], kd[j]);
#pragma unroll
    for (int j = 0; j < 4; ++j) gl2lds16(vp[j], vd[j]);
#pragma unroll
    for (int j = 0; j < 4; ++j) { kp[j] += (size_t)64 * DK; vp[j] += 64; }
    __syncthreads();

    if (k0 >= qw + 16) continue;        // wave-uniform causal skip (tail tiles)

    // ---- S^T = K . Q^T : 4 tiles of 16(key)x16(q) ----
    f32x4 s[4] = {};
#pragma unroll
    for (int kc = 0; kc < 4; ++kc) {
#pragma unroll
      for (int nt = 0; nt < 4; ++nt) {
        bf16x8 kf = *(const bf16x8*)&Ks[(nt * 4 + kc) * 512 + lane * 8];
        s[nt] = __builtin_amdgcn_mfma_f32_16x16x32_bf16(kf, qf[kc], s[nt], 0, 0, 0);
      }
    }

    // ---- softmax (lane holds 16 keys for q = qglob) ----
    float p[4][4];
    float newm = m_run;
    if (k0 + 63 > qw) {  // diagonal tile: per-lane causal mask (wave-uniform branch)
#pragma unroll
      for (int nt = 0; nt < 4; ++nt)
#pragma unroll
        for (int r = 0; r < 4; ++r) {
          int key = k0 + nt * 16 + quad * 4 + r;
          float v = (key <= qglob) ? s[nt][r] : -1e30f;
          p[nt][r] = v;
          newm = fmaxf(newm, v);
        }
    } else {
#pragma unroll
      for (int nt = 0; nt < 4; ++nt)
#pragma unroll
        for (int r = 0; r < 4; ++r) {
          p[nt][r] = s[nt][r];
          newm = fmaxf(newm, s[nt][r]);
        }
    }
    newm = fmaxf(newm, __shfl_xor(newm, 16));
    newm = fmaxf(newm, __shfl_xor(newm, 32));
    float lsum = 0.f;
#pragma unroll
    for (int nt = 0; nt < 4; ++nt)
#pragma unroll
      for (int r = 0; r < 4; ++r) {
        float e = __expf(p[nt][r] - newm);
        p[nt][r] = e;
        lsum += e;
      }
    lsum += __shfl_xor(lsum, 16);
    lsum += __shfl_xor(lsum, 32);
    float alpha = __expf(m_run - newm);
    l_run = l_run * alpha + lsum;
    m_run = newm;

    // ---- P^T write (swizzled, per-wave region; 4 b64 writes) ----
#pragma unroll
    for (int nt = 0; nt < 4; ++nt) {
      u32 lo = (u32)f2b(p[nt][0]) | ((u32)f2b(p[nt][1]) << 16);
      u32 hi = (u32)f2b(p[nt][2]) | ((u32)f2b(p[nt][3]) << 16);
      *(uint2*)&Psw[l16 * 64 + ((nt * 16 + quad * 4) ^ pmask)] = make_uint2(lo, hi);
    }

    // ---- rescale O accumulator ----
#pragma unroll
    for (int r = 0; r < 4; ++r) {
      float av = __shfl(alpha, quad * 4 + r);
#pragma unroll
      for (int nt = 0; nt < 8; ++nt) oacc[nt][r] *= av;
    }

    // ---- PV: O[q][d] += P . V^T ----
#pragma unroll
    for (int kcp = 0; kcp < 2; ++kcp) {
      bf16x8 pf = *(const bf16x8*)&Psw[l16 * 64 + ((kcp * 32 + quad * 8) ^ pmask)];
#pragma unroll
      for (int nt = 0; nt < 8; ++nt) {
        bf16x8 vf = *(const bf16x8*)&Vs[(kcp * 8 + nt) * 512 + lane * 8];
        oacc[nt] = __builtin_amdgcn_mfma_f32_16x16x32_bf16(pf, vf, oacc[nt], 0, 0, 0);
      }
    }
  }

  // ---- epilogue: normalize, stage to LDS, coalesced b128 store ----
  constexpr int LDO = 136;
  float invl = 1.f / l_run;
  __syncthreads();
#pragma unroll
  for (int r = 0; r < 4; ++r) {
    float iv = __shfl(invl, quad * 4 + r);
#pragma unroll
    for (int nt = 0; nt < 8; ++nt)
      smem[(wave * 16 + quad * 4 + r) * LDO + nt * 16 + l16] = f2b(oacc[nt][r] * iv);
  }
  __syncthreads();
  const int b = bh >> 4, h = bh & 15;
#pragma unroll
  for (int pss = 0; pss < 4; ++pss) {
    int row = (t >> 4) + pss * 16;
    uint4 v = *(const uint4*)&smem[row * LDO + (t & 15) * 8];
    *(uint4*)(out + ((size_t)(b * SEQ + qt * 64 + row)) * D_MODEL + h * DK + (t & 15) * 8) = v;
  }
}

// ---------------- host-side orchestration ----------------
extern "C" void kernel_launch(void* const* d_in, const int* in_sizes, int n_in,
                              void* d_out, int out_size, void* d_ws, size_t ws_size,
                              hipStream_t stream) {
  const float* x  = (const float*)d_in[0];
  const float* wq = (const float*)d_in[1];
  const float* wk = (const float*)d_in[2];
  const float* wv = (const float*)d_in[3];
  const float* wo = (const float*)d_in[4];
  const float* bo = (const float*)d_in[5];
  float* out = (float*)d_out;

  char* wsb = (char*)d_ws;
  u16* xb    = (u16*)(wsb + 0);          // 16.78 MB (reused as attn output later)
  u16* wqb   = (u16*)(wsb + 16777216);   //  8.39 MB (wq/wk/wv contiguous => fused B)
  u16* wkb   = (u16*)(wsb + 25165824);
  u16* wvb   = (u16*)(wsb + 33554432);
  u16* wob   = (u16*)(wsb + 41943040);
  u16* Qb    = (u16*)(wsb + 50331648);   // Q/K/V contiguous => fused scatter dest
  u16* Kb    = (u16*)(wsb + 67108864);
  u16* Vb    = (u16*)(wsb + 83886080);
  u16* attnb = xb;                       // x's bf16 copy dead after QKV GEMM
  u16* Vtb   = wqb;                      // weights dead after QKV GEMM (16.78 MB span)

  // 1) convert inputs to bf16
  cvt_k<<<8192, 256, 0, stream>>>(x, xb, MTOT * D_MODEL / 4);
  cvt4_k<<<dim3(4096, 4), 256, 0, stream>>>(wq, wk, wv, wo, wqb, wkb, wvb, wob,
                                            D_MODEL * D_MODEL / 4);

  // 2) fused Q/K/V projection + RoPE (+Q scale): one GEMM, N=6144
  gemm_bt<<<dim3(48, 32), 256, 0, stream>>>(xb, wqb, MTOT, 3 * D_MODEL, D_MODEL,
                                            Qb, nullptr, nullptr, 1);

  // 3) V transpose to (B,H,DK,S)
  vt_k<<<dim3(SEQ / 64, DK / 64, BATCH * NHEADS), 256, 0, stream>>>(Vb, Vtb);

  // 4) causal MFMA flash attention -> (B,S,D_MODEL) bf16
  attn_k<<<dim3(SEQ / 64, BATCH * NHEADS), 256, 0, stream>>>(Qb, Kb, Vtb, attnb);

  // 5) output projection + bias -> fp32 d_out
  gemm_bt<<<dim3(16, 32), 256, 0, stream>>>(attnb, wob, MTOT, D_MODEL, D_MODEL,
                                            nullptr, out, bo, 0);
}